// Round 5
// baseline (898.379 us; speedup 1.0000x reference)
//
#include <hip/hip_runtime.h>

// Attention_18605798326350: B=2,S=2048,DIM=4096,H=32,KVH=8,HD=128, rope theta 5e5, causal.
// R9 == R8 resubmitted (R8 bench died with "MI355X container failed twice" — infra, not kernel;
// bounds/sync/swizzle re-audited clean).
// R8: flash_attn q-widening — BQ=128/block (4 waves x 32 q-rows, 2 subtiles of 16), grid(16,64).
//   Rationale: R7 counters (MfmaUtil 13%, VALU 30%, HBM 6%) => LDS-read-bound; K/V frags were
//   read once per MFMA pair. 32 q-rows/wave reuses each K/V frag 2x => ds_read_b128 per MFMA
//   drops 1.06 -> 0.56. Q now loaded direct global->reg (no LDS staging). LDS 48KB: K 16 | V^T 16
//   | P 4/wave. exp2-domain softmax: log2(e) folded into Q scale (EPI1), v_exp_f32 directly.
// GEMMs unchanged from R7 (256x256 8-phase) except EPI1 scale constant.

#define HN   32
#define KVHN 8
#define HDIM 128
#define SEQ  2048
#define NB   2
#define DIMM 4096
#define KVD  1024

typedef __attribute__((ext_vector_type(4))) float floatx4;
typedef __attribute__((ext_vector_type(8))) short bf16x8;   // 8 bf16 (4 VGPRs)
typedef unsigned short u16;
typedef unsigned int   u32;

__device__ __forceinline__ u16 f2bf(float f) {           // RNE fp32->bf16
  union { float f; u32 u; } x; x.f = f;
  u32 r = x.u + 0x7fffu + ((x.u >> 16) & 1u);
  return (u16)(r >> 16);
}

__device__ __forceinline__ float fexp2(float x) {
#if __has_builtin(__builtin_amdgcn_exp2f)
  return __builtin_amdgcn_exp2f(x);
#else
  return exp2f(x);
#endif
}

// async global->LDS, 16B/lane; LDS dest = wave-uniform base + lane*16
__device__ __forceinline__ void gload_lds16(const u16* g, u16* l) {
  __builtin_amdgcn_global_load_lds(
      (const __attribute__((address_space(1))) void*)g,
      (__attribute__((address_space(3))) void*)l, 16, 0, 0);
}

__global__ __launch_bounds__(256) void cast_f2bf_kernel(const float* __restrict__ in,
                                                        u16* __restrict__ out, int n) {
  int i = (blockIdx.x * 256 + threadIdx.x) * 8;
  if (i + 8 > n) return;
  const float4* p = (const float4*)(in + i);
  float4 a = p[0], b = p[1];
  union { u16 h[8]; uint4 v; } r;
  r.h[0] = f2bf(a.x); r.h[1] = f2bf(a.y); r.h[2] = f2bf(a.z); r.h[3] = f2bf(a.w);
  r.h[4] = f2bf(b.x); r.h[5] = f2bf(b.y); r.h[6] = f2bf(b.z); r.h[7] = f2bf(b.w);
  *(uint4*)(out + i) = r.v;
}

// ---------------- 256x256 8-phase GEMM (unchanged from R7) ----------------
// C[m,n] = sum_k A[m,k]*B[n,k]  (A [M][K], B [N][K] row-major, bf16).
// EPI 1: bf16 + RoPE + log2e/sqrt(HD) scale (Q, exp2-domain).  EPI 2: fp32 out.
// EPI 3: col<1024 -> RoPE+bf16 (K row-major [M][1024]); col>=1024 -> bf16 V^T [2][1024][2048].

#define STG(tile, kind) do {                                                     \
    const int _t = (tile);                                                       \
    if (_t < NT) {                                                               \
      const int _kt = _t << 6;                                                   \
      u16* _buf = smem + ((_t & 1) << 15);                                       \
      const int _isB = (kind) & 1;                                               \
      const u16* _g = _isB ? Bb : Ab;                                            \
      u16* _lb = _isB ? _buf + 16384 : _buf;                                     \
      const int _hh = ((kind) >> 1);                                             \
      _Pragma("unroll")                                                          \
      for (int _cc = 0; _cc < 2; ++_cc) {                                        \
        const int _slot = _cc * 8 + w;                                           \
        const int _rb = _isB ? ((_slot >> 2) * 64 + _hh * 32 + (_slot & 3) * 8)  \
                             : ((_slot >> 3) * 128 + _hh * 64 + (_slot & 7) * 8);\
        const int _lrow = _rb + (l >> 3);                                        \
        const int _ck = (l & 7) ^ (l >> 3);                                      \
        gload_lds16(_g + (long)_lrow * K + _kt + _ck * 8,                        \
                    _lb + _rb * 64);                                             \
      }                                                                          \
    }                                                                            \
  } while (0)

#define LDA(bufAp, mh) do {                                                      \
    _Pragma("unroll") for (int mi = 0; mi < 4; ++mi)                             \
    _Pragma("unroll") for (int kk = 0; kk < 2; ++kk)                             \
      af[mi][kk] = *(const bf16x8*)&(bufAp)[                                     \
          (wm * 128 + (mh) * 64 + mi * 16 + c) * 64 + (((kk * 4 + g) ^ swz) * 8)]; \
  } while (0)

#define LDB(bufBp, nh) do {                                                      \
    _Pragma("unroll") for (int nj = 0; nj < 2; ++nj)                             \
    _Pragma("unroll") for (int kk = 0; kk < 2; ++kk)                             \
      bf[nh][nj][kk] = *(const bf16x8*)&(bufBp)[                                 \
          (wn * 64 + (nh) * 32 + nj * 16 + c) * 64 + (((kk * 4 + g) ^ swz) * 8)]; \
  } while (0)

#define MF16(mh, nh) do {                                                        \
    asm volatile("s_waitcnt lgkmcnt(0)");                                        \
    __builtin_amdgcn_s_setprio(1);                                               \
    _Pragma("unroll") for (int kk = 0; kk < 2; ++kk)                             \
    _Pragma("unroll") for (int mi = 0; mi < 4; ++mi)                             \
    _Pragma("unroll") for (int nj = 0; nj < 2; ++nj)                             \
      acc[mh][mi][nh][nj] = __builtin_amdgcn_mfma_f32_16x16x32_bf16(             \
          af[mi][kk], bf[nh][nj][kk], acc[mh][mi][nh][nj], 0, 0, 0);             \
    __builtin_amdgcn_s_setprio(0);                                               \
  } while (0)

#define BARF() do { asm volatile("" ::: "memory");                               \
                    __builtin_amdgcn_s_barrier();                                \
                    asm volatile("" ::: "memory"); } while (0)

#define HALF_ITER(curA, curB, s1t, s1k, s2t, s2k, s3t, s3k, s4t, s4k, LAST) do { \
    LDA(curA, 0); LDB(curB, 0); STG(s1t, s1k);                                   \
    BARF(); MF16(0, 0); BARF();                                                  \
    LDB(curB, 1); STG(s2t, s2k);                                                 \
    BARF(); MF16(0, 1); BARF();                                                  \
    LDA(curA, 1); STG(s3t, s3k);                                                 \
    BARF(); MF16(1, 0); BARF();                                                  \
    STG(s4t, s4k);                                                               \
    BARF(); MF16(1, 1);                                                          \
    if (LAST) { asm volatile("s_waitcnt vmcnt(0)" ::: "memory"); }               \
    else      { asm volatile("s_waitcnt vmcnt(6)" ::: "memory"); }               \
    BARF();                                                                      \
  } while (0)

template <int EPI>
__global__ __launch_bounds__(512, 2) void gemm256_nt(const u16* __restrict__ A, const u16* __restrict__ B,
                                                     void* __restrict__ Cv, void* __restrict__ Cv2,
                                                     int M, int N, int K,
                                                     const float* __restrict__ fc, const float* __restrict__ fs) {
  __shared__ u16 smem[65536];                           // 128 KiB static LDS
  const int tid = threadIdx.x;
  const int w = tid >> 6, l = tid & 63, g = l >> 4, c = l & 15;
  const int wm = w >> 2, wn = w & 3;
  const int swz = c & 7;

  const int nwg = gridDim.x * gridDim.y;
  int lid = blockIdx.y * gridDim.x + blockIdx.x;
  lid = (lid & 7) * (nwg >> 3) + (lid >> 3);
  const int bx = lid % gridDim.x, by = lid / gridDim.x;
  const int m0 = by * 256, n0 = bx * 256;

  const u16* Ab = A + (long)m0 * K;
  const u16* Bb = B + (long)n0 * K;
  const int NT = K >> 6;
  const int NITER = NT >> 1;

  floatx4 acc[2][4][2][2] = {};
  bf16x8 af[4][2], bf[2][2][2];

  STG(0, 0); STG(0, 1); STG(0, 2); STG(0, 3);
  STG(1, 0); STG(1, 1); STG(1, 2);
  asm volatile("s_waitcnt vmcnt(6)" ::: "memory");
  BARF();

  const u16* A0p = smem;
  const u16* B0p = smem + 16384;
  const u16* A1p = smem + 32768;
  const u16* B1p = smem + 49152;

#pragma unroll 1
  for (int i = 0; i < NITER; ++i) {
    const bool last = (i == NITER - 1);
    const int t2 = 2 * i + 2, t3 = 2 * i + 3;
    HALF_ITER(A0p, B0p, 2 * i + 1, 3, t2, 0, t2, 1, t2, 2, last);
    HALF_ITER(A1p, B1p, t2, 3, t3, 0, t3, 1, t3, 2, last);
  }

#pragma unroll
  for (int mh = 0; mh < 2; ++mh)
#pragma unroll
  for (int mi = 0; mi < 4; ++mi)
#pragma unroll
  for (int nh = 0; nh < 2; ++nh)
#pragma unroll
  for (int nj = 0; nj < 2; ++nj) {
    const int colb = n0 + wn * 64 + nh * 32 + nj * 16;
    const int col = colb + c;
    const int rowb = m0 + wm * 128 + mh * 64 + mi * 16 + g * 4;
    floatx4 av = acc[mh][mi][nh][nj];
    if (EPI == 3 && colb >= 1024) {
      const int bb = rowb >> 11, s0 = rowb & (SEQ - 1);
      union { u16 h4[4]; uint2 v; } pk;
#pragma unroll
      for (int r = 0; r < 4; ++r) pk.h4[r] = f2bf(av[r]);
      *(uint2*)((u16*)Cv2 + ((long)(bb * 1024 + (col - 1024))) * SEQ + s0) = pk.v;
    } else {
#pragma unroll
      for (int r = 0; r < 4; ++r) {
        const int row = rowb + r;
        float v = av[r];
        if (EPI == 1 || EPI == 3) {
          float pv = __shfl_xor(v, 1);
          int pos = row & (SEQ - 1);
          int fi = (col & (HDIM - 1)) >> 1;
          float cs = fc[pos * (HDIM / 2) + fi];
          float sn = fs[pos * (HDIM / 2) + fi];
          v = (col & 1) ? (pv * sn + v * cs) : (v * cs - pv * sn);
          if (EPI == 1) v *= 0.12751744590279677f;   // log2(e)/sqrt(HD): exp2-domain scores
        }
        if (EPI == 2)      ((float*)Cv)[(long)row * N + col] = v;
        else if (EPI == 3) ((u16*)Cv)[(long)row * KVD + col] = f2bf(v);
        else               ((u16*)Cv)[(long)row * N + col] = f2bf(v);
      }
    }
  }
}

// Flash attention, S^T orientation. grid(16, B*H). BQ=128 (4 waves x 32 q-rows: 2 subtiles
// of 16), BK=64. Q direct global->reg. LDS: sK 64x128 [0,8192) | sVT 128x64 [8192,16384) |
// per-wave P 32x64 [16384,24576). 48KB. Swizzle: 16B chunk k -> k^(row&7) ((row&7)==(c&7)
// for both subtiles since sub stride 16). K/V frags each feed BOTH subtiles (2x reuse).
// Softmax in exp2 domain (scores pre-scaled by log2e in Q epilogue).
// Pipeline per tile j: QK(j) | sync1 | stageK(j+1) | softmax+PV(j) | sync2 | stageV(j+1).
__global__ __launch_bounds__(256) void flash_attn(const u16* __restrict__ q, const u16* __restrict__ kk,
                                                  const u16* __restrict__ vt, u16* __restrict__ o) {
  __shared__ u16 smem[24576];
  const int tid = threadIdx.x;
  const int w = tid >> 6, l = tid & 63, g = (l >> 4) & 3, c = l & 15;
  const int bh = blockIdx.y, b = bh >> 5, h = bh & 31, kvh = h >> 2;
  const int q0 = (15 - blockIdx.x) * 128;          // heavy (causal) blocks first

  const u16* qg = q  + (long)(b * SEQ + q0) * DIMM + h * HDIM;
  const u16* kg = kk + (long)b * SEQ * KVD + kvh * HDIM;
  const u16* vg = vt + (long)(b * KVD + kvh * HDIM) * SEQ;   // V^T rows d, stride SEQ

  const int r4 = l >> 4, ka16 = l & 15, r8 = l >> 3, ka8 = l & 7;

  // Q direct to regs: lane (g,c) sub t -> Q[q0 + w*32 + sub*16 + c][t*32 + g*8 .. +8]
  bf16x8 qf[2][4];
#pragma unroll
  for (int sub = 0; sub < 2; ++sub)
#pragma unroll
    for (int t = 0; t < 4; ++t)
      qf[sub][t] = *(const bf16x8*)(qg + (long)(w * 32 + sub * 16 + c) * DIMM + t * 32 + g * 8);

  u16* sP = &smem[16384 + w * 2048];               // per-wave 32x64 P tile
  floatx4 oacc[2][8] = {};
  float mrow[2] = {-3e38f, -3e38f}, lrow[2] = {0.f, 0.f};
  const int nkt = (q0 >> 6) + 2;
  const int qw0 = q0 + w * 32;

  // prologue: stage K(0), V(0)
#pragma unroll
  for (int cc = 0; cc < 4; ++cc) {
    int srow = cc * 16 + w * 4 + r4;
    gload_lds16(kg + (long)srow * KVD + ((ka16 ^ (srow & 7)) * 8), &smem[(cc * 16 + w * 4) * 128]);
  }
#pragma unroll
  for (int cc = 0; cc < 4; ++cc) {
    int drow = cc * 32 + w * 8 + r8;
    gload_lds16(vg + (long)drow * SEQ + ((ka8 ^ (drow & 7)) * 8), &smem[8192 + (cc * 32 + w * 8) * 64]);
  }
  __syncthreads();                                  // drain K0,V0 (and Q reg loads complete via waits)

  for (int j = 0; j < nkt; ++j) {
    // St = K * Q^T : frag rows = s (g*4+r), cols = q (c). Each kf frag used by both subtiles.
    floatx4 sc[2][4] = {};
#pragma unroll
    for (int ms = 0; ms < 4; ++ms) {
      bf16x8 kf[4];
#pragma unroll
      for (int t = 0; t < 4; ++t)
        kf[t] = *(const bf16x8*)&smem[(ms * 16 + c) * 128 + ((t * 4 + g) ^ (c & 7)) * 8];
#pragma unroll
      for (int t = 0; t < 4; ++t) {
        sc[0][ms] = __builtin_amdgcn_mfma_f32_16x16x32_bf16(kf[t], qf[0][t], sc[0][ms], 0, 0, 0);
        sc[1][ms] = __builtin_amdgcn_mfma_f32_16x16x32_bf16(kf[t], qf[1][t], sc[1][ms], 0, 0, 0);
      }
    }
    __syncthreads();                                // Kbuf free; drains V(j)

    if (j + 1 < nkt) {                              // stage K(j+1) — drains at sync2
#pragma unroll
      for (int cc = 0; cc < 4; ++cc) {
        int srow = cc * 16 + w * 4 + r4;
        gload_lds16(kg + (long)((j + 1) * 64 + srow) * KVD + ((ka16 ^ (srow & 7)) * 8),
                    &smem[(cc * 16 + w * 4) * 128]);
      }
    }

    // softmax (per-lane row q = sub*16 + c, exp2 domain) + P pack
#pragma unroll
    for (int sub = 0; sub < 2; ++sub) {
      const bool needMask = (j * 64 + 63) > (qw0 + sub * 16);   // wave-uniform
      const int qv = qw0 + sub * 16 + c;
      float mx = -3e38f;
#pragma unroll
      for (int ms = 0; ms < 4; ++ms) {
        const int sbase = j * 64 + ms * 16 + g * 4;
#pragma unroll
        for (int r = 0; r < 4; ++r) {
          float v = sc[sub][ms][r];
          if (needMask && (sbase + r > qv)) v = -1e9f;
          sc[sub][ms][r] = v;
          mx = fmaxf(mx, v);
        }
      }
      mx = fmaxf(mx, __shfl_xor(mx, 16));
      mx = fmaxf(mx, __shfl_xor(mx, 32));
      const float mnew = fmaxf(mrow[sub], mx);
      const float alpha = fexp2(mrow[sub] - mnew);
      mrow[sub] = mnew;
      float rs = 0.f;
#pragma unroll
      for (int ms = 0; ms < 4; ++ms)
#pragma unroll
        for (int r = 0; r < 4; ++r) {
          float p = fexp2(sc[sub][ms][r] - mnew);
          sc[sub][ms][r] = p;
          rs += p;
        }
      rs += __shfl_xor(rs, 16);
      rs += __shfl_xor(rs, 32);
      lrow[sub] = lrow[sub] * alpha + rs;
#pragma unroll
      for (int md = 0; md < 8; ++md) oacc[sub][md] *= alpha;
#pragma unroll
      for (int ms = 0; ms < 4; ++ms) {              // pack P (bf16) to per-wave LDS tile
        u32 lo = (u32)f2bf(sc[sub][ms][0]) | ((u32)f2bf(sc[sub][ms][1]) << 16);
        u32 hi = (u32)f2bf(sc[sub][ms][2]) | ((u32)f2bf(sc[sub][ms][3]) << 16);
        uint2 val; val.x = lo; val.y = hi;
        const int sc16 = ms * 2 + (g >> 1);
        *(uint2*)&sP[(sub * 16 + c) * 64 + ((sc16 ^ (c & 7)) * 8) + (g & 1) * 4] = val;
      }
    }

    // O^T += V^T * P^T   (V(j) drained at sync1; P same-wave LDS order). vf used by both subs.
    bf16x8 pf[2][2];
#pragma unroll
    for (int sub = 0; sub < 2; ++sub)
#pragma unroll
      for (int kb2 = 0; kb2 < 2; ++kb2)
        pf[sub][kb2] = *(const bf16x8*)&sP[(sub * 16 + c) * 64 + (((kb2 * 4 + g) ^ (c & 7)) * 8)];
#pragma unroll
    for (int md = 0; md < 8; ++md)
#pragma unroll
      for (int kb2 = 0; kb2 < 2; ++kb2) {
        bf16x8 vf = *(const bf16x8*)&smem[8192 + (md * 16 + c) * 64 + (((kb2 * 4 + g) ^ (c & 7)) * 8)];
        oacc[0][md] = __builtin_amdgcn_mfma_f32_16x16x32_bf16(vf, pf[0][kb2], oacc[0][md], 0, 0, 0);
        oacc[1][md] = __builtin_amdgcn_mfma_f32_16x16x32_bf16(vf, pf[1][kb2], oacc[1][md], 0, 0, 0);
      }
    __syncthreads();                                // Vbuf free; drains K(j+1)

    if (j + 1 < nkt) {                              // stage V(j+1) — drains at next sync1
#pragma unroll
      for (int cc = 0; cc < 4; ++cc) {
        int drow = cc * 32 + w * 8 + r8;
        gload_lds16(vg + (long)drow * SEQ + (j + 1) * 64 + ((ka8 ^ (drow & 7)) * 8),
                    &smem[8192 + (cc * 32 + w * 8) * 64]);
      }
    }
  }

  // epilogue: O^T frag -> O row-major; lane: q = sub*16 + c, d = md*16 + g*4 + r
#pragma unroll
  for (int sub = 0; sub < 2; ++sub) {
    u16* ob = o + (long)(b * SEQ + q0 + w * 32 + sub * 16) * DIMM + h * HDIM;
    const float inv = 1.f / lrow[sub];
#pragma unroll
    for (int md = 0; md < 8; ++md) {
      union { u16 h4[4]; uint2 v; } pk;
#pragma unroll
      for (int r = 0; r < 4; ++r) pk.h4[r] = f2bf(oacc[sub][md][r] * inv);
      *(uint2*)&ob[(long)c * DIMM + md * 16 + g * 4] = pk.v;
    }
  }
}

extern "C" void kernel_launch(void* const* d_in, const int* in_sizes, int n_in,
                              void* d_out, int out_size, void* d_ws, size_t ws_size,
                              hipStream_t stream) {
  (void)in_sizes; (void)n_in; (void)out_size; (void)ws_size;
  const float* x  = (const float*)d_in[0];
  const float* wq = (const float*)d_in[1];
  const float* wk = (const float*)d_in[2];
  const float* wv = (const float*)d_in[3];
  const float* wo = (const float*)d_in[4];
  const float* fc = (const float*)d_in[5];
  const float* fs = (const float*)d_in[6];

  u16* xb  = (u16*)d_ws;            // 16777216
  u16* w16 = xb  + 16777216;        // 16777216
  u16* qb  = w16 + 16777216;        // 16777216
  u16* kb  = qb  + 16777216;        //  4194304
  u16* vT  = kb  + 4194304;         //  4194304  V^T [2][1024][2048]
  u16* ab  = vT  + 4194304;         // 16777216

  const int M = NB * SEQ;           // 4096

  cast_f2bf_kernel<<<16777216 / 2048, 256, 0, stream>>>(x,  xb,  16777216);
  cast_f2bf_kernel<<<16777216 / 2048, 256, 0, stream>>>(wq, w16, 16777216);
  gemm256_nt<1><<<dim3(16, 16), 512, 0, stream>>>(xb, w16, qb, nullptr, M, DIMM, DIMM, fc, fs);
  cast_f2bf_kernel<<<4194304 / 2048, 256, 0, stream>>>(wk, w16, 4194304);
  cast_f2bf_kernel<<<4194304 / 2048, 256, 0, stream>>>(wv, w16 + 4194304, 4194304);
  gemm256_nt<3><<<dim3(8, 16), 512, 0, stream>>>(xb, w16, kb, vT, M, 2048, DIMM, fc, fs);
  flash_attn<<<dim3(16, 64), 256, 0, stream>>>(qb, kb, vT, ab);
  cast_f2bf_kernel<<<16777216 / 2048, 256, 0, stream>>>(wo, w16, 16777216);
  gemm256_nt<2><<<dim3(16, 16), 512, 0, stream>>>(ab, w16, d_out, nullptr, M, DIMM, DIMM, nullptr, nullptr);
}

// Round 6
// 718.736 us; speedup vs baseline: 1.2499x; 1.2499x over previous
//
#include <hip/hip_runtime.h>

// Attention_18605798326350: B=2,S=2048,DIM=4096,H=32,KVH=8,HD=128, rope theta 5e5, causal.
// R10: revert flash_attn to R7 structure (16 q-rows/wave, BQ=64, 40KB LDS) — R9's q-widening
//   regressed (occupancy 20%->6.4%, dur 222->328: latency/imbalance-bound, not LDS-BW-bound).
//   New: (1) TRIANGLE BALANCING — grid(16,64); block x runs q-tile (31-x) then q-tile x
//   sequentially => every block does exactly 33 K-tiles; 1024 uniform blocks = exactly
//   4 blocks/CU (40KB LDS), no tail. (2) exp2-domain softmax kept (log2e in Q scale).
//   (3) v_cvt_pk_bf16_f32 for P-pack and O epilogue (saves ~60 VALU instr/wave-tile).
//   Q loaded direct global->reg per pass.
// GEMMs unchanged (256x256 8-phase, R7-verified).

#define HN   32
#define KVHN 8
#define HDIM 128
#define SEQ  2048
#define NB   2
#define DIMM 4096
#define KVD  1024

typedef __attribute__((ext_vector_type(4))) float floatx4;
typedef __attribute__((ext_vector_type(8))) short bf16x8;   // 8 bf16 (4 VGPRs)
typedef unsigned short u16;
typedef unsigned int   u32;

__device__ __forceinline__ u16 f2bf(float f) {           // RNE fp32->bf16
  union { float f; u32 u; } x; x.f = f;
  u32 r = x.u + 0x7fffu + ((x.u >> 16) & 1u);
  return (u16)(r >> 16);
}

__device__ __forceinline__ u32 cvtpk_bf16(float a, float b) {  // {lo=bf16(a), hi=bf16(b)}
  u32 r;
  asm("v_cvt_pk_bf16_f32 %0, %1, %2" : "=v"(r) : "v"(a), "v"(b));
  return r;
}

__device__ __forceinline__ float fexp2(float x) {
#if __has_builtin(__builtin_amdgcn_exp2f)
  return __builtin_amdgcn_exp2f(x);
#else
  return exp2f(x);
#endif
}

// async global->LDS, 16B/lane; LDS dest = wave-uniform base + lane*16
__device__ __forceinline__ void gload_lds16(const u16* g, u16* l) {
  __builtin_amdgcn_global_load_lds(
      (const __attribute__((address_space(1))) void*)g,
      (__attribute__((address_space(3))) void*)l, 16, 0, 0);
}

__global__ __launch_bounds__(256) void cast_f2bf_kernel(const float* __restrict__ in,
                                                        u16* __restrict__ out, int n) {
  int i = (blockIdx.x * 256 + threadIdx.x) * 8;
  if (i + 8 > n) return;
  const float4* p = (const float4*)(in + i);
  float4 a = p[0], b = p[1];
  union { u16 h[8]; uint4 v; } r;
  r.h[0] = f2bf(a.x); r.h[1] = f2bf(a.y); r.h[2] = f2bf(a.z); r.h[3] = f2bf(a.w);
  r.h[4] = f2bf(b.x); r.h[5] = f2bf(b.y); r.h[6] = f2bf(b.z); r.h[7] = f2bf(b.w);
  *(uint4*)(out + i) = r.v;
}

// ---------------- 256x256 8-phase GEMM (unchanged from R7) ----------------
// C[m,n] = sum_k A[m,k]*B[n,k]  (A [M][K], B [N][K] row-major, bf16).
// EPI 1: bf16 + RoPE + log2e/sqrt(HD) scale (Q, exp2-domain).  EPI 2: fp32 out.
// EPI 3: col<1024 -> RoPE+bf16 (K row-major [M][1024]); col>=1024 -> bf16 V^T [2][1024][2048].

#define STG(tile, kind) do {                                                     \
    const int _t = (tile);                                                       \
    if (_t < NT) {                                                               \
      const int _kt = _t << 6;                                                   \
      u16* _buf = smem + ((_t & 1) << 15);                                       \
      const int _isB = (kind) & 1;                                               \
      const u16* _g = _isB ? Bb : Ab;                                            \
      u16* _lb = _isB ? _buf + 16384 : _buf;                                     \
      const int _hh = ((kind) >> 1);                                             \
      _Pragma("unroll")                                                          \
      for (int _cc = 0; _cc < 2; ++_cc) {                                        \
        const int _slot = _cc * 8 + w;                                           \
        const int _rb = _isB ? ((_slot >> 2) * 64 + _hh * 32 + (_slot & 3) * 8)  \
                             : ((_slot >> 3) * 128 + _hh * 64 + (_slot & 7) * 8);\
        const int _lrow = _rb + (l >> 3);                                        \
        const int _ck = (l & 7) ^ (l >> 3);                                      \
        gload_lds16(_g + (long)_lrow * K + _kt + _ck * 8,                        \
                    _lb + _rb * 64);                                             \
      }                                                                          \
    }                                                                            \
  } while (0)

#define LDA(bufAp, mh) do {                                                      \
    _Pragma("unroll") for (int mi = 0; mi < 4; ++mi)                             \
    _Pragma("unroll") for (int kk = 0; kk < 2; ++kk)                             \
      af[mi][kk] = *(const bf16x8*)&(bufAp)[                                     \
          (wm * 128 + (mh) * 64 + mi * 16 + c) * 64 + (((kk * 4 + g) ^ swz) * 8)]; \
  } while (0)

#define LDB(bufBp, nh) do {                                                      \
    _Pragma("unroll") for (int nj = 0; nj < 2; ++nj)                             \
    _Pragma("unroll") for (int kk = 0; kk < 2; ++kk)                             \
      bf[nh][nj][kk] = *(const bf16x8*)&(bufBp)[                                 \
          (wn * 64 + (nh) * 32 + nj * 16 + c) * 64 + (((kk * 4 + g) ^ swz) * 8)]; \
  } while (0)

#define MF16(mh, nh) do {                                                        \
    asm volatile("s_waitcnt lgkmcnt(0)");                                        \
    __builtin_amdgcn_s_setprio(1);                                               \
    _Pragma("unroll") for (int kk = 0; kk < 2; ++kk)                             \
    _Pragma("unroll") for (int mi = 0; mi < 4; ++mi)                             \
    _Pragma("unroll") for (int nj = 0; nj < 2; ++nj)                             \
      acc[mh][mi][nh][nj] = __builtin_amdgcn_mfma_f32_16x16x32_bf16(             \
          af[mi][kk], bf[nh][nj][kk], acc[mh][mi][nh][nj], 0, 0, 0);             \
    __builtin_amdgcn_s_setprio(0);                                               \
  } while (0)

#define BARF() do { asm volatile("" ::: "memory");                               \
                    __builtin_amdgcn_s_barrier();                                \
                    asm volatile("" ::: "memory"); } while (0)

#define HALF_ITER(curA, curB, s1t, s1k, s2t, s2k, s3t, s3k, s4t, s4k, LAST) do { \
    LDA(curA, 0); LDB(curB, 0); STG(s1t, s1k);                                   \
    BARF(); MF16(0, 0); BARF();                                                  \
    LDB(curB, 1); STG(s2t, s2k);                                                 \
    BARF(); MF16(0, 1); BARF();                                                  \
    LDA(curA, 1); STG(s3t, s3k);                                                 \
    BARF(); MF16(1, 0); BARF();                                                  \
    STG(s4t, s4k);                                                               \
    BARF(); MF16(1, 1);                                                          \
    if (LAST) { asm volatile("s_waitcnt vmcnt(0)" ::: "memory"); }               \
    else      { asm volatile("s_waitcnt vmcnt(6)" ::: "memory"); }               \
    BARF();                                                                      \
  } while (0)

template <int EPI>
__global__ __launch_bounds__(512, 2) void gemm256_nt(const u16* __restrict__ A, const u16* __restrict__ B,
                                                     void* __restrict__ Cv, void* __restrict__ Cv2,
                                                     int M, int N, int K,
                                                     const float* __restrict__ fc, const float* __restrict__ fs) {
  __shared__ u16 smem[65536];                           // 128 KiB static LDS
  const int tid = threadIdx.x;
  const int w = tid >> 6, l = tid & 63, g = l >> 4, c = l & 15;
  const int wm = w >> 2, wn = w & 3;
  const int swz = c & 7;

  const int nwg = gridDim.x * gridDim.y;
  int lid = blockIdx.y * gridDim.x + blockIdx.x;
  lid = (lid & 7) * (nwg >> 3) + (lid >> 3);
  const int bx = lid % gridDim.x, by = lid / gridDim.x;
  const int m0 = by * 256, n0 = bx * 256;

  const u16* Ab = A + (long)m0 * K;
  const u16* Bb = B + (long)n0 * K;
  const int NT = K >> 6;
  const int NITER = NT >> 1;

  floatx4 acc[2][4][2][2] = {};
  bf16x8 af[4][2], bf[2][2][2];

  STG(0, 0); STG(0, 1); STG(0, 2); STG(0, 3);
  STG(1, 0); STG(1, 1); STG(1, 2);
  asm volatile("s_waitcnt vmcnt(6)" ::: "memory");
  BARF();

  const u16* A0p = smem;
  const u16* B0p = smem + 16384;
  const u16* A1p = smem + 32768;
  const u16* B1p = smem + 49152;

#pragma unroll 1
  for (int i = 0; i < NITER; ++i) {
    const bool last = (i == NITER - 1);
    const int t2 = 2 * i + 2, t3 = 2 * i + 3;
    HALF_ITER(A0p, B0p, 2 * i + 1, 3, t2, 0, t2, 1, t2, 2, last);
    HALF_ITER(A1p, B1p, t2, 3, t3, 0, t3, 1, t3, 2, last);
  }

#pragma unroll
  for (int mh = 0; mh < 2; ++mh)
#pragma unroll
  for (int mi = 0; mi < 4; ++mi)
#pragma unroll
  for (int nh = 0; nh < 2; ++nh)
#pragma unroll
  for (int nj = 0; nj < 2; ++nj) {
    const int colb = n0 + wn * 64 + nh * 32 + nj * 16;
    const int col = colb + c;
    const int rowb = m0 + wm * 128 + mh * 64 + mi * 16 + g * 4;
    floatx4 av = acc[mh][mi][nh][nj];
    if (EPI == 3 && colb >= 1024) {
      const int bb = rowb >> 11, s0 = rowb & (SEQ - 1);
      union { u16 h4[4]; uint2 v; } pk;
#pragma unroll
      for (int r = 0; r < 4; ++r) pk.h4[r] = f2bf(av[r]);
      *(uint2*)((u16*)Cv2 + ((long)(bb * 1024 + (col - 1024))) * SEQ + s0) = pk.v;
    } else {
#pragma unroll
      for (int r = 0; r < 4; ++r) {
        const int row = rowb + r;
        float v = av[r];
        if (EPI == 1 || EPI == 3) {
          float pv = __shfl_xor(v, 1);
          int pos = row & (SEQ - 1);
          int fi = (col & (HDIM - 1)) >> 1;
          float cs = fc[pos * (HDIM / 2) + fi];
          float sn = fs[pos * (HDIM / 2) + fi];
          v = (col & 1) ? (pv * sn + v * cs) : (v * cs - pv * sn);
          if (EPI == 1) v *= 0.12751744590279677f;   // log2(e)/sqrt(HD): exp2-domain scores
        }
        if (EPI == 2)      ((float*)Cv)[(long)row * N + col] = v;
        else if (EPI == 3) ((u16*)Cv)[(long)row * KVD + col] = f2bf(v);
        else               ((u16*)Cv)[(long)row * N + col] = f2bf(v);
      }
    }
  }
}

// Flash attention, S^T orientation. grid(16, B*H). Triangle-balanced: block x runs q-tile
// (31-x) then q-tile x => exactly 33 K-tiles per block, 1024 uniform blocks = 4/CU (40KB LDS).
// Per pass: BQ=64 (4 waves x 16 q-rows), BK=64. Q direct global->reg.
// LDS: sK 64x128 [0,8192) | sVT 128x64 [8192,16384) | per-wave P 16x64 [16384,20480). 40KB.
// Swizzle: 16B chunk k -> k^(row&7). Softmax exp2-domain (log2e folded into Q scale).
// Pipeline per tile j: QK(j) | sync1 | stageK(j+1) | softmax+PV(j) | sync2 | stageV(j+1).
// Pass-1 prologue staging is safe: pass-0's last sync2 (after PV) ordered all LDS reads.
__global__ __launch_bounds__(256) void flash_attn(const u16* __restrict__ q, const u16* __restrict__ kk,
                                                  const u16* __restrict__ vt, u16* __restrict__ o) {
  __shared__ u16 smem[20480];
  const int tid = threadIdx.x;
  const int w = tid >> 6, l = tid & 63, g = (l >> 4) & 3, c = l & 15;
  const int bh = blockIdx.y, b = bh >> 5, h = bh & 31, kvh = h >> 2;
  const int r4 = l >> 4, ka16 = l & 15, r8 = l >> 3, ka8 = l & 7;

  const u16* kg = kk + (long)b * SEQ * KVD + kvh * HDIM;
  const u16* vg = vt + (long)(b * KVD + kvh * HDIM) * SEQ;   // V^T rows d, stride SEQ
  u16* sP = &smem[16384 + w * 1024];                // per-wave 16x64 P tile

#pragma unroll 1
  for (int pass = 0; pass < 2; ++pass) {
    const int qblk = pass ? (int)blockIdx.x : 31 - (int)blockIdx.x;   // heavy pass first
    const int q0 = qblk * 64;
    const u16* qg = q + (long)(b * SEQ + q0) * DIMM + h * HDIM;

    // Q direct to regs: lane (g,c) frag t -> Q[q0 + w*16 + c][t*32 + g*8 .. +8]
    bf16x8 qf[4];
#pragma unroll
    for (int t = 0; t < 4; ++t)
      qf[t] = *(const bf16x8*)(qg + (long)(w * 16 + c) * DIMM + t * 32 + g * 8);

    floatx4 oacc[8] = {};
    float mrow = -3e38f, lrow = 0.f;
    const int nkt = qblk + 1;
    const int qwave = q0 + w * 16;

    // prologue: stage K(0), V(0)
#pragma unroll
    for (int cc = 0; cc < 4; ++cc) {
      int srow = cc * 16 + w * 4 + r4;
      gload_lds16(kg + (long)srow * KVD + ((ka16 ^ (srow & 7)) * 8), &smem[(cc * 16 + w * 4) * 128]);
    }
#pragma unroll
    for (int cc = 0; cc < 4; ++cc) {
      int drow = cc * 32 + w * 8 + r8;
      gload_lds16(vg + (long)drow * SEQ + ((ka8 ^ (drow & 7)) * 8), &smem[8192 + (cc * 32 + w * 8) * 64]);
    }
    __syncthreads();                                // drain K0,V0

    for (int j = 0; j < nkt; ++j) {
      // St = K * Q^T : frag rows = s (g*4+r), cols = q (c). Scores pre-scaled (Q epilogue).
      floatx4 sc[4] = {};
#pragma unroll
      for (int ms = 0; ms < 4; ++ms) {
        bf16x8 kf[4];
#pragma unroll
        for (int t = 0; t < 4; ++t)
          kf[t] = *(const bf16x8*)&smem[(ms * 16 + c) * 128 + ((t * 4 + g) ^ (c & 7)) * 8];
#pragma unroll
        for (int t = 0; t < 4; ++t)
          sc[ms] = __builtin_amdgcn_mfma_f32_16x16x32_bf16(kf[t], qf[t], sc[ms], 0, 0, 0);
      }
      __syncthreads();                              // Kbuf free; drains V(j)

      if (j + 1 < nkt) {                            // stage K(j+1) — drains at sync2
#pragma unroll
        for (int cc = 0; cc < 4; ++cc) {
          int srow = cc * 16 + w * 4 + r4;
          gload_lds16(kg + (long)((j + 1) * 64 + srow) * KVD + ((ka16 ^ (srow & 7)) * 8),
                      &smem[(cc * 16 + w * 4) * 128]);
        }
      }

      { // softmax (per-lane row q = c, exp2 domain) + P pack via v_cvt_pk_bf16_f32
        const bool needMask = (j * 64 + 63) > qwave;  // wave-uniform (last tile only)
        const int qv = qwave + c;
        float mx = -3e38f;
#pragma unroll
        for (int ms = 0; ms < 4; ++ms) {
          const int sbase = j * 64 + ms * 16 + g * 4;
#pragma unroll
          for (int r = 0; r < 4; ++r) {
            float v = sc[ms][r];
            if (needMask && (sbase + r > qv)) v = -1e9f;
            sc[ms][r] = v;
            mx = fmaxf(mx, v);
          }
        }
        mx = fmaxf(mx, __shfl_xor(mx, 16));
        mx = fmaxf(mx, __shfl_xor(mx, 32));
        const float mnew = fmaxf(mrow, mx);
        const float alpha = fexp2(mrow - mnew);
        mrow = mnew;
        float rs = 0.f;
#pragma unroll
        for (int ms = 0; ms < 4; ++ms)
#pragma unroll
          for (int r = 0; r < 4; ++r) {
            float p = fexp2(sc[ms][r] - mnew);
            sc[ms][r] = p;
            rs += p;
          }
        rs += __shfl_xor(rs, 16);
        rs += __shfl_xor(rs, 32);
        lrow = lrow * alpha + rs;
#pragma unroll
        for (int md = 0; md < 8; ++md) oacc[md] *= alpha;
#pragma unroll
        for (int ms = 0; ms < 4; ++ms) {            // pack P (bf16) to per-wave LDS tile
          uint2 val;
          val.x = cvtpk_bf16(sc[ms][0], sc[ms][1]);
          val.y = cvtpk_bf16(sc[ms][2], sc[ms][3]);
          const int sc16 = ms * 2 + (g >> 1);
          *(uint2*)&sP[c * 64 + ((sc16 ^ (c & 7)) * 8) + (g & 1) * 4] = val;
        }
      }

      // O^T += V^T * P^T   (V(j) drained at sync1; P same-wave LDS order)
      bf16x8 pf[2];
#pragma unroll
      for (int kb2 = 0; kb2 < 2; ++kb2)
        pf[kb2] = *(const bf16x8*)&sP[c * 64 + (((kb2 * 4 + g) ^ (c & 7)) * 8)];
#pragma unroll
      for (int md = 0; md < 8; ++md)
#pragma unroll
        for (int kb2 = 0; kb2 < 2; ++kb2) {
          bf16x8 vf = *(const bf16x8*)&smem[8192 + (md * 16 + c) * 64 + (((kb2 * 4 + g) ^ (c & 7)) * 8)];
          oacc[md] = __builtin_amdgcn_mfma_f32_16x16x32_bf16(vf, pf[kb2], oacc[md], 0, 0, 0);
        }
      __syncthreads();                              // Vbuf free; drains K(j+1)

      if (j + 1 < nkt) {                            // stage V(j+1) — drains at next sync1
#pragma unroll
        for (int cc = 0; cc < 4; ++cc) {
          int drow = cc * 32 + w * 8 + r8;
          gload_lds16(vg + (long)drow * SEQ + (j + 1) * 64 + ((ka8 ^ (drow & 7)) * 8),
                      &smem[8192 + (cc * 32 + w * 8) * 64]);
        }
      }
    }

    // epilogue: O^T frag -> O row-major; lane: q = c, d = md*16 + g*4 + r
    u16* ob = o + (long)(b * SEQ + q0 + w * 16) * DIMM + h * HDIM;
    const float inv = 1.f / lrow;
#pragma unroll
    for (int md = 0; md < 8; ++md) {
      uint2 pk;
      pk.x = cvtpk_bf16(oacc[md][0] * inv, oacc[md][1] * inv);
      pk.y = cvtpk_bf16(oacc[md][2] * inv, oacc[md][3] * inv);
      *(uint2*)&ob[(long)c * DIMM + md * 16 + g * 4] = pk;
    }
  }
}

extern "C" void kernel_launch(void* const* d_in, const int* in_sizes, int n_in,
                              void* d_out, int out_size, void* d_ws, size_t ws_size,
                              hipStream_t stream) {
  (void)in_sizes; (void)n_in; (void)out_size; (void)ws_size;
  const float* x  = (const float*)d_in[0];
  const float* wq = (const float*)d_in[1];
  const float* wk = (const float*)d_in[2];
  const float* wv = (const float*)d_in[3];
  const float* wo = (const float*)d_in[4];
  const float* fc = (const float*)d_in[5];
  const float* fs = (const float*)d_in[6];

  u16* xb  = (u16*)d_ws;            // 16777216
  u16* w16 = xb  + 16777216;        // 16777216
  u16* qb  = w16 + 16777216;        // 16777216
  u16* kb  = qb  + 16777216;        //  4194304
  u16* vT  = kb  + 4194304;         //  4194304  V^T [2][1024][2048]
  u16* ab  = vT  + 4194304;         // 16777216

  const int M = NB * SEQ;           // 4096

  cast_f2bf_kernel<<<16777216 / 2048, 256, 0, stream>>>(x,  xb,  16777216);
  cast_f2bf_kernel<<<16777216 / 2048, 256, 0, stream>>>(wq, w16, 16777216);
  gemm256_nt<1><<<dim3(16, 16), 512, 0, stream>>>(xb, w16, qb, nullptr, M, DIMM, DIMM, fc, fs);
  cast_f2bf_kernel<<<4194304 / 2048, 256, 0, stream>>>(wk, w16, 4194304);
  cast_f2bf_kernel<<<4194304 / 2048, 256, 0, stream>>>(wv, w16 + 4194304, 4194304);
  gemm256_nt<3><<<dim3(8, 16), 512, 0, stream>>>(xb, w16, kb, vT, M, 2048, DIMM, fc, fs);
  flash_attn<<<dim3(16, 64), 256, 0, stream>>>(qb, kb, vT, ab);
  cast_f2bf_kernel<<<16777216 / 2048, 256, 0, stream>>>(wo, w16, 16777216);
  gemm256_nt<2><<<dim3(16, 16), 512, 0, stream>>>(ab, w16, d_out, nullptr, M, DIMM, DIMM, nullptr, nullptr);
}